// Round 1
// baseline (85.799 us; speedup 1.0000x reference)
//
#include <hip/hip_runtime.h>

#define S_TOT 2048
#define B_SZ  32
#define I_SZ  256
#define O_SZ  80

typedef _Float16 f16x8 __attribute__((ext_vector_type(8)));
typedef _Float16 f16x4 __attribute__((ext_vector_type(4)));
typedef float    f32x4 __attribute__((ext_vector_type(4)));

// One block per subsystem s. 320 threads = 5 waves; wave w owns output
// columns [16w, 16w+16). LDS holds X (32x256 f16, 16KB) and W (80x256 f16,
// 40KB), both XOR-swizzled (byte ^= (row&7)<<4) so mfma fragment ds_read_b128
// at row-stride 512B is conflict-free (T2). 56KB LDS -> 2 blocks/CU.
__global__ __launch_bounds__(320) void dcell_kernel(
    const float* __restrict__ x,        // [S, 32, 256]
    const float* __restrict__ W,        // [S, 80, 256]
    const float* __restrict__ bias,     // [S, 80]
    const float* __restrict__ gamma,    // [S, 80]
    const float* __restrict__ beta,     // [S, 80]
    const float* __restrict__ out_mask, // [S, 80]
    float* __restrict__ out)            // [S, 32, 80]
{
  __shared__ char smem[57344];
  char* Xs = smem;           // 32 rows * 512B
  char* Ws = smem + 16384;   // 80 rows * 512B

  const int s   = blockIdx.x;
  const int tid = threadIdx.x;

  // ---- stage X: f32 -> f16, swizzled. 2048 float4 chunks.
  {
    const float* xg = x + (size_t)s * (B_SZ * I_SZ);
    for (int t = tid; t < (B_SZ * I_SZ) / 4; t += 320) {
      f32x4 v = *(const f32x4*)(xg + t * 4);
      int flat = t * 4;
      int r = flat >> 8, c = flat & 255;
      int off = r * 512 + ((c * 2) ^ ((r & 7) << 4));
      f16x4 h;
      h[0] = (_Float16)v[0]; h[1] = (_Float16)v[1];
      h[2] = (_Float16)v[2]; h[3] = (_Float16)v[3];
      *(f16x4*)(Xs + off) = h;
    }
  }
  // ---- stage W: 5120 float4 chunks (exactly 16 per thread).
  {
    const float* wg = W + (size_t)s * (O_SZ * I_SZ);
    for (int t = tid; t < (O_SZ * I_SZ) / 4; t += 320) {
      f32x4 v = *(const f32x4*)(wg + t * 4);
      int flat = t * 4;
      int r = flat >> 8, c = flat & 255;
      int off = r * 512 + ((c * 2) ^ ((r & 7) << 4));
      f16x4 h;
      h[0] = (_Float16)v[0]; h[1] = (_Float16)v[1];
      h[2] = (_Float16)v[2]; h[3] = (_Float16)v[3];
      *(f16x4*)(Ws + off) = h;
    }
  }
  __syncthreads();

  // ---- per-wave GEMM: two 16x16 tiles (b=0..15, b=16..31), K=256
  const int w  = tid >> 6;   // wave 0..4 -> o-chunk
  const int l  = tid & 63;
  const int m  = l & 15;     // A row / B col within tile
  const int ks = l >> 4;     // k-slice 0..3
  const int ob = w * 16;
  const int swz = (m & 7) << 4;

  f32x4 acc0 = {0.f, 0.f, 0.f, 0.f};
  f32x4 acc1 = {0.f, 0.f, 0.f, 0.f};
  const char* xr0 = Xs + m * 512;
  const char* xr1 = Xs + (m + 16) * 512;       // (m+16)&7 == m&7
  const char* wr  = Ws + (ob + m) * 512;       // ob%8==0 -> same swz
#pragma unroll
  for (int kc = 0; kc < 8; ++kc) {
    int kb = (kc * 64 + ks * 16) ^ swz;
    f16x8 a0 = *(const f16x8*)(xr0 + kb);
    f16x8 a1 = *(const f16x8*)(xr1 + kb);
    f16x8 bb = *(const f16x8*)(wr + kb);
    acc0 = __builtin_amdgcn_mfma_f32_16x16x32_f16(a0, bb, acc0, 0, 0, 0);
    acc1 = __builtin_amdgcn_mfma_f32_16x16x32_f16(a1, bb, acc1, 0, 0, 0);
  }

  // ---- epilogue: bias, tanh, BatchNorm over b (in-register), mask, store.
  // C layout (m89): col = lane&15, row = (lane>>4)*4 + reg.
  const int o = ob + m;
  const float bv = bias[s * O_SZ + o];
  float t0[4], t1[4];
  float sum = 0.f;
#pragma unroll
  for (int r = 0; r < 4; ++r) {
    t0[r] = tanhf(acc0[r] + bv);
    t1[r] = tanhf(acc1[r] + bv);
    sum += t0[r] + t1[r];
  }
  sum += __shfl_xor(sum, 16);
  sum += __shfl_xor(sum, 32);
  const float mean = sum * (1.0f / 32.0f);

  float vs = 0.f;
#pragma unroll
  for (int r = 0; r < 4; ++r) {
    float d0 = t0[r] - mean, d1 = t1[r] - mean;
    vs += d0 * d0 + d1 * d1;
  }
  vs += __shfl_xor(vs, 16);
  vs += __shfl_xor(vs, 32);
  const float rstd = rsqrtf(vs * (1.0f / 32.0f) + 1e-5f);

  const float g  = gamma[s * O_SZ + o] * rstd;
  const float be = beta[s * O_SZ + o];
  const float om = out_mask[s * O_SZ + o];

  float* og = out + (size_t)s * (B_SZ * O_SZ) + o;
#pragma unroll
  for (int r = 0; r < 4; ++r) {
    int b0 = ks * 4 + r;
    og[(size_t)b0 * O_SZ]        = ((t0[r] - mean) * g + be) * om;
    og[(size_t)(b0 + 16) * O_SZ] = ((t1[r] - mean) * g + be) * om;
  }
}

extern "C" void kernel_launch(void* const* d_in, const int* in_sizes, int n_in,
                              void* d_out, int out_size, void* d_ws, size_t ws_size,
                              hipStream_t stream) {
  const float* x        = (const float*)d_in[0];
  const float* W        = (const float*)d_in[1];
  const float* bias     = (const float*)d_in[2];
  const float* gamma    = (const float*)d_in[3];
  const float* beta     = (const float*)d_in[4];
  // d_in[5] = in_mask: unused (x is pre-masked, padded entries exactly 0)
  const float* out_mask = (const float*)d_in[6];
  float* out = (float*)d_out;

  dcell_kernel<<<dim3(S_TOT), dim3(320), 0, stream>>>(
      x, W, bias, gamma, beta, out_mask, out);
}

// Round 2
// 44.744 us; speedup vs baseline: 1.9176x; 1.9176x over previous
//
#include <hip/hip_runtime.h>

#define S_TOT 2048
#define B_SZ  32
#define I_SZ  256
#define O_SZ  80

typedef _Float16 f16x8 __attribute__((ext_vector_type(8)));
typedef _Float16 f16x4 __attribute__((ext_vector_type(4)));
typedef float    f32x4 __attribute__((ext_vector_type(4)));

// One block per subsystem s. 320 threads = 5 waves; wave w owns output
// columns [16w, 16w+16). LDS holds ONLY X (32x256 f16, 16KB, XOR-swizzled
// byte ^= (row&7)<<4 so mfma fragment ds_read_b128 at row-stride 512B is
// conflict-free). W has no inter-wave reuse -> loaded global->reg directly
// (per-lane fragment addressing), overlapped with X staging.
// 16KB LDS + VGPR<=102 -> 4 blocks/CU = 20 waves.
__global__ __launch_bounds__(320, 5) void dcell_kernel(
    const float* __restrict__ x,        // [S, 32, 256]
    const float* __restrict__ W,        // [S, 80, 256]
    const float* __restrict__ bias,     // [S, 80]
    const float* __restrict__ gamma,    // [S, 80]
    const float* __restrict__ beta,     // [S, 80]
    const float* __restrict__ out_mask, // [S, 80]
    float* __restrict__ out)            // [S, 32, 80]
{
  __shared__ char Xs[16384];  // 32 rows * 512B

  const int s   = blockIdx.x;
  const int tid = threadIdx.x;

  const int w  = tid >> 6;   // wave 0..4 -> o-chunk
  const int l  = tid & 63;
  const int m  = l & 15;     // A row / B col within tile
  const int ks = l >> 4;     // k-slice 0..3
  const int ob = w * 16;
  const int swz = (m & 7) << 4;

  // ---- stage X: f32 -> f16, swizzled. 2048 float4 chunks (issued first).
  {
    const float* xg = x + (size_t)s * (B_SZ * I_SZ);
    for (int t = tid; t < (B_SZ * I_SZ) / 4; t += 320) {
      f32x4 v = *(const f32x4*)(xg + t * 4);
      int flat = t * 4;
      int r = flat >> 8, c = flat & 255;
      int off = r * 512 + ((c * 2) ^ ((r & 7) << 4));
      f16x4 h;
      h[0] = (_Float16)v[0]; h[1] = (_Float16)v[1];
      h[2] = (_Float16)v[2]; h[3] = (_Float16)v[3];
      *(f16x4*)(Xs + off) = h;
    }
  }

  // ---- W fragments: global -> reg, f32 -> f16. Lane (m,ks) of wave w holds
  // W[ob+m][kc*32 + ks*8 .. +8) for kc=0..7. Same k-map as the A-fragment
  // LDS reads below, so the MFMA dot products line up.
  f16x8 wf[8];
  {
    const float* wgp = W + ((size_t)s * O_SZ + ob + m) * I_SZ + ks * 8;
#pragma unroll
    for (int kc = 0; kc < 8; ++kc) {
      f32x4 lo = *(const f32x4*)(wgp + kc * 32);
      f32x4 hi = *(const f32x4*)(wgp + kc * 32 + 4);
      f16x8 h;
      h[0] = (_Float16)lo[0]; h[1] = (_Float16)lo[1];
      h[2] = (_Float16)lo[2]; h[3] = (_Float16)lo[3];
      h[4] = (_Float16)hi[0]; h[5] = (_Float16)hi[1];
      h[6] = (_Float16)hi[2]; h[7] = (_Float16)hi[3];
      wf[kc] = h;
    }
  }
  __syncthreads();

  // ---- per-wave GEMM: two 16x16 tiles (b=0..15, b=16..31), K=256
  f32x4 acc0 = {0.f, 0.f, 0.f, 0.f};
  f32x4 acc1 = {0.f, 0.f, 0.f, 0.f};
  const char* xr0 = Xs + m * 512;
  const char* xr1 = Xs + (m + 16) * 512;       // (m+16)&7 == m&7
#pragma unroll
  for (int kc = 0; kc < 8; ++kc) {
    int kb = (kc * 64 + ks * 16) ^ swz;
    f16x8 a0 = *(const f16x8*)(xr0 + kb);
    f16x8 a1 = *(const f16x8*)(xr1 + kb);
    acc0 = __builtin_amdgcn_mfma_f32_16x16x32_f16(a0, wf[kc], acc0, 0, 0, 0);
    acc1 = __builtin_amdgcn_mfma_f32_16x16x32_f16(a1, wf[kc], acc1, 0, 0, 0);
  }

  // ---- epilogue: bias, tanh, BatchNorm over b (in-register), mask, store.
  // C layout (m89): col = lane&15, row = (lane>>4)*4 + reg.
  const int o = ob + m;
  const float bv = bias[s * O_SZ + o];
  float t0[4], t1[4];
  float sum = 0.f;
#pragma unroll
  for (int r = 0; r < 4; ++r) {
    t0[r] = tanhf(acc0[r] + bv);
    t1[r] = tanhf(acc1[r] + bv);
    sum += t0[r] + t1[r];
  }
  sum += __shfl_xor(sum, 16);
  sum += __shfl_xor(sum, 32);
  const float mean = sum * (1.0f / 32.0f);

  float vs = 0.f;
#pragma unroll
  for (int r = 0; r < 4; ++r) {
    float d0 = t0[r] - mean, d1 = t1[r] - mean;
    vs += d0 * d0 + d1 * d1;
  }
  vs += __shfl_xor(vs, 16);
  vs += __shfl_xor(vs, 32);
  const float rstd = rsqrtf(vs * (1.0f / 32.0f) + 1e-5f);

  const float g  = gamma[s * O_SZ + o] * rstd;
  const float be = beta[s * O_SZ + o];
  const float om = out_mask[s * O_SZ + o];

  float* og = out + (size_t)s * (B_SZ * O_SZ) + o;
#pragma unroll
  for (int r = 0; r < 4; ++r) {
    int b0 = ks * 4 + r;
    og[(size_t)b0 * O_SZ]        = ((t0[r] - mean) * g + be) * om;
    og[(size_t)(b0 + 16) * O_SZ] = ((t1[r] - mean) * g + be) * om;
  }
}

extern "C" void kernel_launch(void* const* d_in, const int* in_sizes, int n_in,
                              void* d_out, int out_size, void* d_ws, size_t ws_size,
                              hipStream_t stream) {
  const float* x        = (const float*)d_in[0];
  const float* W        = (const float*)d_in[1];
  const float* bias     = (const float*)d_in[2];
  const float* gamma    = (const float*)d_in[3];
  const float* beta     = (const float*)d_in[4];
  // d_in[5] = in_mask: unused (x is pre-masked, padded entries exactly 0)
  const float* out_mask = (const float*)d_in[6];
  float* out = (float*)d_out;

  dcell_kernel<<<dim3(S_TOT), dim3(320), 0, stream>>>(
      x, W, bias, gamma, beta, out_mask, out);
}

// Round 3
// 35.699 us; speedup vs baseline: 2.4034x; 1.2534x over previous
//
#include <hip/hip_runtime.h>

#define S_TOT 2048
#define B_SZ  32
#define I_SZ  256
#define O_SZ  80

typedef _Float16 f16x8 __attribute__((ext_vector_type(8)));
typedef _Float16 f16x4 __attribute__((ext_vector_type(4)));
typedef float    f32x4 __attribute__((ext_vector_type(4)));

// One block per subsystem s. 320 threads = 5 waves; wave w owns output
// columns [16w, 16w+16). LDS holds ONLY X (32x256 f16, 16KB, XOR-swizzled
// byte ^= (row&7)<<4 -> mfma fragment ds_read_b128 conflict-free). W has no
// inter-wave reuse -> global->reg. RAGGED-K: x is pre-masked to zero beyond
// in_size, so K-chunks >= ceil(in_size/32) contribute exactly 0 -> skip
// their x reads, W reads, and MFMAs (avg active K ~154/256 -> ~40% less
// traffic). kcmax derived from in_mask (prefix-ones: chunk k active iff
// mask[32k]==1), block-uniform.
__global__ __launch_bounds__(320, 5) void dcell_kernel(
    const float* __restrict__ x,        // [S, 32, 256]
    const float* __restrict__ W,        // [S, 80, 256]
    const float* __restrict__ bias,     // [S, 80]
    const float* __restrict__ gamma,    // [S, 80]
    const float* __restrict__ beta,     // [S, 80]
    const float* __restrict__ in_mask,  // [S, 256]
    const float* __restrict__ out_mask, // [S, 80]
    float* __restrict__ out)            // [S, 32, 80]
{
  __shared__ char Xs[16384];  // 32 rows * 512B

  const int s   = blockIdx.x;
  const int tid = threadIdx.x;

  // ---- active K-chunk count (block-uniform, scalar loads)
  const float* im = in_mask + (size_t)s * I_SZ;
  float msum = im[0] + im[32] + im[64] + im[96] +
               im[128] + im[160] + im[192] + im[224];
  const int kcmax = (int)(msum + 0.5f);   // 1..8
  const int Kact  = kcmax * 32;

  const int w  = tid >> 6;   // wave 0..4 -> o-chunk
  const int l  = tid & 63;
  const int m  = l & 15;     // A row / B col within tile
  const int ks = l >> 4;     // k-slice 0..3
  const int ob = w * 16;
  const int swz = (m & 7) << 4;

  // ---- stage X: f32 -> f16, swizzled; only active columns (per-lane guard).
  {
    const float* xg = x + (size_t)s * (B_SZ * I_SZ);
    for (int t = tid; t < (B_SZ * I_SZ) / 4; t += 320) {
      int flat = t * 4;
      int r = flat >> 8, c = flat & 255;
      if (c < Kact) {
        f32x4 v = *(const f32x4*)(xg + flat);
        int off = r * 512 + ((c * 2) ^ ((r & 7) << 4));
        f16x4 h;
        h[0] = (_Float16)v[0]; h[1] = (_Float16)v[1];
        h[2] = (_Float16)v[2]; h[3] = (_Float16)v[3];
        *(f16x4*)(Xs + off) = h;
      }
    }
  }

  // ---- W fragments: global -> reg, f32 -> f16, active chunks only.
  // Lane (m,ks) of wave w holds W[ob+m][kc*32 + ks*8 .. +8). Same k-map as
  // the A-fragment LDS reads, so MFMA dot products line up.
  f16x8 wf[8];
  {
    const float* wgp = W + ((size_t)s * O_SZ + ob + m) * I_SZ + ks * 8;
#pragma unroll
    for (int kc = 0; kc < 8; ++kc) {
      if (kc < kcmax) {
        f32x4 lo = *(const f32x4*)(wgp + kc * 32);
        f32x4 hi = *(const f32x4*)(wgp + kc * 32 + 4);
        f16x8 h;
        h[0] = (_Float16)lo[0]; h[1] = (_Float16)lo[1];
        h[2] = (_Float16)lo[2]; h[3] = (_Float16)lo[3];
        h[4] = (_Float16)hi[0]; h[5] = (_Float16)hi[1];
        h[6] = (_Float16)hi[2]; h[7] = (_Float16)hi[3];
        wf[kc] = h;
      }
    }
  }
  __syncthreads();

  // ---- per-wave GEMM: two 16x16 tiles (b=0..15, b=16..31), K=Kact
  f32x4 acc0 = {0.f, 0.f, 0.f, 0.f};
  f32x4 acc1 = {0.f, 0.f, 0.f, 0.f};
  const char* xr0 = Xs + m * 512;
  const char* xr1 = Xs + (m + 16) * 512;       // (m+16)&7 == m&7
#pragma unroll
  for (int kc = 0; kc < 8; ++kc) {
    if (kc < kcmax) {
      int kb = (kc * 64 + ks * 16) ^ swz;
      f16x8 a0 = *(const f16x8*)(xr0 + kb);
      f16x8 a1 = *(const f16x8*)(xr1 + kb);
      acc0 = __builtin_amdgcn_mfma_f32_16x16x32_f16(a0, wf[kc], acc0, 0, 0, 0);
      acc1 = __builtin_amdgcn_mfma_f32_16x16x32_f16(a1, wf[kc], acc1, 0, 0, 0);
    }
  }

  // ---- epilogue: bias, tanh, BatchNorm over b (in-register), mask, store.
  // C layout (m89): col = lane&15, row = (lane>>4)*4 + reg.
  const int o = ob + m;
  const float bv = bias[s * O_SZ + o];
  float t0[4], t1[4];
  float sum = 0.f;
#pragma unroll
  for (int r = 0; r < 4; ++r) {
    t0[r] = tanhf(acc0[r] + bv);
    t1[r] = tanhf(acc1[r] + bv);
    sum += t0[r] + t1[r];
  }
  sum += __shfl_xor(sum, 16);
  sum += __shfl_xor(sum, 32);
  const float mean = sum * (1.0f / 32.0f);

  float vs = 0.f;
#pragma unroll
  for (int r = 0; r < 4; ++r) {
    float d0 = t0[r] - mean, d1 = t1[r] - mean;
    vs += d0 * d0 + d1 * d1;
  }
  vs += __shfl_xor(vs, 16);
  vs += __shfl_xor(vs, 32);
  const float rstd = rsqrtf(vs * (1.0f / 32.0f) + 1e-5f);

  const float g  = gamma[s * O_SZ + o] * rstd;
  const float be = beta[s * O_SZ + o];
  const float om = out_mask[s * O_SZ + o];

  float* og = out + (size_t)s * (B_SZ * O_SZ) + o;
#pragma unroll
  for (int r = 0; r < 4; ++r) {
    int b0 = ks * 4 + r;
    og[(size_t)b0 * O_SZ]        = ((t0[r] - mean) * g + be) * om;
    og[(size_t)(b0 + 16) * O_SZ] = ((t1[r] - mean) * g + be) * om;
  }
}

extern "C" void kernel_launch(void* const* d_in, const int* in_sizes, int n_in,
                              void* d_out, int out_size, void* d_ws, size_t ws_size,
                              hipStream_t stream) {
  const float* x        = (const float*)d_in[0];
  const float* W        = (const float*)d_in[1];
  const float* bias     = (const float*)d_in[2];
  const float* gamma    = (const float*)d_in[3];
  const float* beta     = (const float*)d_in[4];
  const float* in_mask  = (const float*)d_in[5];
  const float* out_mask = (const float*)d_in[6];
  float* out = (float*)d_out;

  dcell_kernel<<<dim3(S_TOT), dim3(320), 0, stream>>>(
      x, W, bias, gamma, beta, in_mask, out_mask, out);
}

// Round 4
// 29.369 us; speedup vs baseline: 2.9214x; 1.2155x over previous
//
#include <hip/hip_runtime.h>

#define S_TOT 2048
#define B_SZ  32
#define I_SZ  256
#define O_SZ  80

typedef _Float16 f16x8 __attribute__((ext_vector_type(8)));
typedef _Float16 f16x4 __attribute__((ext_vector_type(4)));
typedef float    f32x4 __attribute__((ext_vector_type(4)));

// One block per subsystem s. 320 threads = 5 waves; wave w owns output
// columns [16w, 16w+16). LDS holds ONLY X (32x256 f16, 16KB, XOR-swizzled
// byte ^= (row&7)<<4 -> mfma fragment ds_read_b128 conflict-free). W has no
// inter-wave reuse -> global->reg.
// RAGGED-K: x pre-masked to zero beyond in_size -> skip K-chunks >=
//   ceil(in_size/32) (x reads, W reads, MFMAs). kcmax from in_mask
//   (prefix-ones: chunk k active iff mask[32k]==1), block-uniform.
// RAGGED-O: final *out_mask zeroes o >= out_size, and BN is per-(s,o), so
//   W rows for masked o are irrelevant (avg 43/80 active). Waves whose
//   o-chunk is fully masked skip W/MFMA/epilogue and store zeros; partially
//   masked lanes skip W loads (wf zeroed -> NaN-free, om=0 path exact).
__global__ __launch_bounds__(320, 5) void dcell_kernel(
    const float* __restrict__ x,        // [S, 32, 256]
    const float* __restrict__ W,        // [S, 80, 256]
    const float* __restrict__ bias,     // [S, 80]
    const float* __restrict__ gamma,    // [S, 80]
    const float* __restrict__ beta,     // [S, 80]
    const float* __restrict__ in_mask,  // [S, 256]
    const float* __restrict__ out_mask, // [S, 80]
    float* __restrict__ out)            // [S, 32, 80]
{
  __shared__ char Xs[16384];  // 32 rows * 512B

  const int s   = blockIdx.x;
  const int tid = threadIdx.x;

  const int w  = tid >> 6;   // wave 0..4 -> o-chunk
  const int l  = tid & 63;
  const int m  = l & 15;     // A row / B col within tile
  const int ks = l >> 4;     // k-slice 0..3
  const int ob = w * 16;
  const int o  = ob + m;
  const int swz = (m & 7) << 4;

  // ---- active K-chunk count (block-uniform, scalar loads)
  const float* im = in_mask + (size_t)s * I_SZ;
  float msum = im[0] + im[32] + im[64] + im[96] +
               im[128] + im[160] + im[192] + im[224];
  const int kcmax = (int)(msum + 0.5f);   // 1..8
  const int Kact  = kcmax * 32;

  // ---- out_size via per-wave butterfly reduce of out_mask (prefix-ones)
  const float* omp = out_mask + (size_t)s * O_SZ;
  float osum = omp[l] + ((l < 16) ? omp[64 + l] : 0.f);
#pragma unroll
  for (int d = 32; d; d >>= 1) osum += __shfl_xor(osum, d);
  const int out_sz = (int)(osum + 0.5f);   // 20..80
  const bool wave_act = (ob < out_sz);
  const bool lane_act = (o < out_sz);

  // ---- stage X: f32 -> f16, swizzled; only active columns (per-lane guard).
  {
    const float* xg = x + (size_t)s * (B_SZ * I_SZ);
    for (int t = tid; t < (B_SZ * I_SZ) / 4; t += 320) {
      int flat = t * 4;
      int r = flat >> 8, c = flat & 255;
      if (c < Kact) {
        f32x4 v = *(const f32x4*)(xg + flat);
        int off = r * 512 + ((c * 2) ^ ((r & 7) << 4));
        f16x4 h;
        h[0] = (_Float16)v[0]; h[1] = (_Float16)v[1];
        h[2] = (_Float16)v[2]; h[3] = (_Float16)v[3];
        *(f16x4*)(Xs + off) = h;
      }
    }
  }

  // ---- W fragments: global -> reg, f32 -> f16; active chunks AND active
  // o-rows only. Lane (m,ks) of wave w holds W[o][kc*32 + ks*8 .. +8).
  f16x8 wf[8];
  {
    const float* wgp = W + ((size_t)s * O_SZ + o) * I_SZ + ks * 8;
#pragma unroll
    for (int kc = 0; kc < 8; ++kc) {
      if (kc < kcmax) {
        f16x8 h = {0, 0, 0, 0, 0, 0, 0, 0};
        if (lane_act) {
          f32x4 lo = *(const f32x4*)(wgp + kc * 32);
          f32x4 hi = *(const f32x4*)(wgp + kc * 32 + 4);
          h[0] = (_Float16)lo[0]; h[1] = (_Float16)lo[1];
          h[2] = (_Float16)lo[2]; h[3] = (_Float16)lo[3];
          h[4] = (_Float16)hi[0]; h[5] = (_Float16)hi[1];
          h[6] = (_Float16)hi[2]; h[7] = (_Float16)hi[3];
        }
        wf[kc] = h;
      }
    }
  }
  __syncthreads();

  float* og = out + (size_t)s * (B_SZ * O_SZ) + o;

  if (wave_act) {
    // ---- per-wave GEMM: two 16x16 tiles (b=0..15, b=16..31), K=Kact
    f32x4 acc0 = {0.f, 0.f, 0.f, 0.f};
    f32x4 acc1 = {0.f, 0.f, 0.f, 0.f};
    const char* xr0 = Xs + m * 512;
    const char* xr1 = Xs + (m + 16) * 512;     // (m+16)&7 == m&7
#pragma unroll
    for (int kc = 0; kc < 8; ++kc) {
      if (kc < kcmax) {
        int kb = (kc * 64 + ks * 16) ^ swz;
        f16x8 a0 = *(const f16x8*)(xr0 + kb);
        f16x8 a1 = *(const f16x8*)(xr1 + kb);
        acc0 = __builtin_amdgcn_mfma_f32_16x16x32_f16(a0, wf[kc], acc0, 0, 0, 0);
        acc1 = __builtin_amdgcn_mfma_f32_16x16x32_f16(a1, wf[kc], acc1, 0, 0, 0);
      }
    }

    // ---- epilogue: bias, tanh, BatchNorm over b (in-register), mask, store.
    // C layout (m89): col = lane&15, row = (lane>>4)*4 + reg.
    const float bv = bias[s * O_SZ + o];
    float t0[4], t1[4];
    float sum = 0.f;
#pragma unroll
    for (int r = 0; r < 4; ++r) {
      t0[r] = tanhf(acc0[r] + bv);
      t1[r] = tanhf(acc1[r] + bv);
      sum += t0[r] + t1[r];
    }
    sum += __shfl_xor(sum, 16);
    sum += __shfl_xor(sum, 32);
    const float mean = sum * (1.0f / 32.0f);

    float vs = 0.f;
#pragma unroll
    for (int r = 0; r < 4; ++r) {
      float d0 = t0[r] - mean, d1 = t1[r] - mean;
      vs += d0 * d0 + d1 * d1;
    }
    vs += __shfl_xor(vs, 16);
    vs += __shfl_xor(vs, 32);
    const float rstd = rsqrtf(vs * (1.0f / 32.0f) + 1e-5f);

    const float g  = gamma[s * O_SZ + o] * rstd;
    const float be = beta[s * O_SZ + o];
    const float om = omp[o];

#pragma unroll
    for (int r = 0; r < 4; ++r) {
      int b0 = ks * 4 + r;
      og[(size_t)b0 * O_SZ]        = ((t0[r] - mean) * g + be) * om;
      og[(size_t)(b0 + 16) * O_SZ] = ((t1[r] - mean) * g + be) * om;
    }
  } else {
    // fully-masked o-chunk: output is exactly 0 (and d_out is poisoned).
#pragma unroll
    for (int r = 0; r < 4; ++r) {
      int b0 = ks * 4 + r;
      og[(size_t)b0 * O_SZ]        = 0.f;
      og[(size_t)(b0 + 16) * O_SZ] = 0.f;
    }
  }
}

extern "C" void kernel_launch(void* const* d_in, const int* in_sizes, int n_in,
                              void* d_out, int out_size, void* d_ws, size_t ws_size,
                              hipStream_t stream) {
  const float* x        = (const float*)d_in[0];
  const float* W        = (const float*)d_in[1];
  const float* bias     = (const float*)d_in[2];
  const float* gamma    = (const float*)d_in[3];
  const float* beta     = (const float*)d_in[4];
  const float* in_mask  = (const float*)d_in[5];
  const float* out_mask = (const float*)d_in[6];
  float* out = (float*)d_out;

  dcell_kernel<<<dim3(S_TOT), dim3(320), 0, stream>>>(
      x, W, bias, gamma, beta, in_mask, out_mask, out);
}